// Round 1
// baseline (408.066 us; speedup 1.0000x reference)
//
#include <hip/hip_runtime.h>

constexpr int NL    = 48;
constexpr int SEQ   = 1024;
constexpr int BATCH = 512;

__device__ __forceinline__ float lane_bcast(float v, int lane) {
    return __int_as_float(__builtin_amdgcn_readlane(__float_as_int(v), lane));
}

// One step of the linear-domain forward recurrence.
// v_next[j] = (sum_i v[i] * E[i][j]) * exp(emit[t][j]), masked.
#define CRF_STEP(T_, SLOT_) do {                                              \
    float ee_ = __expf(embuf[SLOT_]);                                         \
    int   mt_ = mbuf[SLOT_];                                                  \
    int   tn_ = (T_) + 8; if (tn_ > SEQ - 1) tn_ = SEQ - 1;                   \
    embuf[SLOT_] = em[tn_ * NL + jc];                                         \
    mbuf[SLOT_]  = mk[tn_];                                                   \
    float a0_ = 0.f, a1_ = 0.f, a2_ = 0.f, a3_ = 0.f;                         \
    _Pragma("unroll")                                                         \
    for (int i_ = 0; i_ < NL; i_ += 4) {                                      \
        a0_ = fmaf(lane_bcast(v, i_ + 0), Ec[i_ + 0], a0_);                   \
        a1_ = fmaf(lane_bcast(v, i_ + 1), Ec[i_ + 1], a1_);                   \
        a2_ = fmaf(lane_bcast(v, i_ + 2), Ec[i_ + 2], a2_);                   \
        a3_ = fmaf(lane_bcast(v, i_ + 3), Ec[i_ + 3], a3_);                   \
    }                                                                         \
    float acc_ = (a0_ + a1_) + (a2_ + a3_);                                   \
    v = mt_ ? acc_ * ee_ : v;                                                 \
} while (0)

// Rescale v by its wave-max, fold into log-scale S. Every 4 steps.
#define CRF_RENORM do {                                                       \
    float m_ = v;                                                             \
    _Pragma("unroll")                                                         \
    for (int o_ = 32; o_; o_ >>= 1) m_ = fmaxf(m_, __shfl_xor(m_, o_));       \
    float r_ = 1.0f / m_;                                                     \
    v *= r_;                                                                  \
    S += __logf(m_);                                                          \
} while (0)

__global__ __launch_bounds__(64) void crf_forward(
    const float* __restrict__ emissions, const int* __restrict__ mask,
    const float* __restrict__ trans, const float* __restrict__ startt,
    const float* __restrict__ endt, float* __restrict__ fwd_out)
{
    const int  b   = blockIdx.x;
    const int  j   = threadIdx.x;          // 0..63, lanes 48..63 idle (v=0)
    const bool act = (j < NL);
    const int  jc  = act ? j : NL - 1;

    // E column j in registers: Ec[i] = exp(T[i][j]); forward uses T[prev][cur].
    float Ec[NL];
    #pragma unroll
    for (int i = 0; i < NL; ++i) {
        float t = trans[i * NL + jc];      // consecutive lanes -> consecutive addrs
        Ec[i] = act ? __expf(t) : 0.0f;
    }

    const float* em = emissions + (size_t)b * SEQ * NL;
    const int*   mk = mask + b * SEQ;

    // init: score0 = start + emit[0]; normalize by wave max.
    float s0 = act ? (startt[jc] + em[jc]) : -3.0e38f;
    float m0 = s0;
    #pragma unroll
    for (int o = 32; o; o >>= 1) m0 = fmaxf(m0, __shfl_xor(m0, o));
    float v = act ? __expf(s0 - m0) : 0.0f;
    float S = m0;

    // 8-deep prefetch ring for emissions + mask (static slot indices only).
    float embuf[8]; int mbuf[8];
    #pragma unroll
    for (int t = 1; t <= 8; ++t) { embuf[t & 7] = em[t * NL + jc]; mbuf[t & 7] = mk[t]; }

    // peeled steps 1..7; renorm before every t with t%4==1 (t>1).
    CRF_STEP(1, 1); CRF_STEP(2, 2); CRF_STEP(3, 3); CRF_STEP(4, 4);
    CRF_RENORM;
    CRF_STEP(5, 5); CRF_STEP(6, 6); CRF_STEP(7, 7);

    // aligned chunks of 8: tb = 8,16,...,1016 covers t = 8..1023.
    for (int tb = 8; tb <= SEQ - 8; tb += 8) {
        CRF_STEP(tb + 0, 0);
        CRF_RENORM;
        CRF_STEP(tb + 1, 1); CRF_STEP(tb + 2, 2); CRF_STEP(tb + 3, 3); CRF_STEP(tb + 4, 4);
        CRF_RENORM;
        CRF_STEP(tb + 5, 5); CRF_STEP(tb + 6, 6); CRF_STEP(tb + 7, 7);
    }

    // fwd = S + log(sum_j v[j] * exp(end[j]))
    float w = act ? v * __expf(endt[jc]) : 0.0f;
    #pragma unroll
    for (int o = 32; o; o >>= 1) w += __shfl_xor(w, o);
    if (j == 0) fwd_out[b] = S + __logf(w);
}

__global__ __launch_bounds__(64) void crf_gold(
    const float* __restrict__ emissions, const int* __restrict__ labels,
    const int* __restrict__ mask, const float* __restrict__ trans,
    const float* __restrict__ startt, const float* __restrict__ endt,
    float* __restrict__ gold_out)
{
    const int b = blockIdx.x;
    const int l = threadIdx.x;
    const int*   lb = labels + b * SEQ;
    const int*   mk = mask + b * SEQ;
    const float* em = emissions + (size_t)b * SEQ * NL;

    float part = 0.0f; int mcnt = 0;
    for (int t = l; t < SEQ; t += 64) {
        int lt = lb[t];
        int mt = mk[t];
        mcnt += mt;
        if (t == 0) {
            part += startt[lt] + em[lt];
        } else {
            float e  = em[t * NL + lt];
            float tr = trans[lt * NL + lb[t - 1]];   // gold uses T[cur][prev]
            if (mt) part += e + tr;
        }
    }
    #pragma unroll
    for (int o = 32; o; o >>= 1) {
        part += __shfl_xor(part, o);
        mcnt += __shfl_xor(mcnt, o);
    }
    if (l == 0) {
        int len = mcnt - 1;
        gold_out[b] = part + endt[lb[len]];
    }
}

__global__ __launch_bounds__(64) void crf_reduce(
    const float* __restrict__ gold, const float* __restrict__ fwd,
    float* __restrict__ out)
{
    const int l = threadIdx.x;
    float s = 0.0f;
    for (int bIdx = l; bIdx < BATCH; bIdx += 64) s += fwd[bIdx] - gold[bIdx];
    #pragma unroll
    for (int o = 32; o; o >>= 1) s += __shfl_xor(s, o);
    if (l == 0) out[0] = s * (1.0f / (float)BATCH);
}

extern "C" void kernel_launch(void* const* d_in, const int* in_sizes, int n_in,
                              void* d_out, int out_size, void* d_ws, size_t ws_size,
                              hipStream_t stream) {
    const float* emissions = (const float*)d_in[0];
    const int*   labels    = (const int*)d_in[1];
    const int*   mask      = (const int*)d_in[2];
    const float* trans     = (const float*)d_in[3];
    const float* startt    = (const float*)d_in[4];
    const float* endt      = (const float*)d_in[5];
    float*       out       = (float*)d_out;
    float*       wsf       = (float*)d_ws;   // [0..512) gold, [512..1024) fwd

    crf_gold<<<BATCH, 64, 0, stream>>>(emissions, labels, mask, trans, startt, endt, wsf);
    crf_forward<<<BATCH, 64, 0, stream>>>(emissions, mask, trans, startt, endt, wsf + BATCH);
    crf_reduce<<<1, 64, 0, stream>>>(wsf, wsf + BATCH, out);
}

// Round 2
// 398.959 us; speedup vs baseline: 1.0228x; 1.0228x over previous
//
#include <hip/hip_runtime.h>

constexpr int NL    = 48;
constexpr int SEQ   = 1024;
constexpr int BATCH = 512;

__device__ __forceinline__ float lane_bcast(float v, int lane) {
    return __int_as_float(__builtin_amdgcn_readlane(__float_as_int(v), lane));
}

// One step of the linear-domain forward recurrence.
// v_next[j] = (sum_i v[i] * E[i][j]) * exp(emit[t][j]), masked.
#define CRF_STEP(T_, SLOT_) do {                                              \
    float ee_ = __expf(embuf[SLOT_]);                                         \
    int   mt_ = mbuf[SLOT_];                                                  \
    int   tn_ = (T_) + 8; if (tn_ > SEQ - 1) tn_ = SEQ - 1;                   \
    embuf[SLOT_] = em[tn_ * NL + jc];                                         \
    mbuf[SLOT_]  = mk[tn_];                                                   \
    float a0_ = 0.f, a1_ = 0.f, a2_ = 0.f, a3_ = 0.f;                         \
    _Pragma("unroll")                                                         \
    for (int i_ = 0; i_ < NL; i_ += 4) {                                      \
        a0_ = fmaf(lane_bcast(v, i_ + 0), Ec[i_ + 0], a0_);                   \
        a1_ = fmaf(lane_bcast(v, i_ + 1), Ec[i_ + 1], a1_);                   \
        a2_ = fmaf(lane_bcast(v, i_ + 2), Ec[i_ + 2], a2_);                   \
        a3_ = fmaf(lane_bcast(v, i_ + 3), Ec[i_ + 3], a3_);                   \
    }                                                                         \
    float acc_ = (a0_ + a1_) + (a2_ + a3_);                                   \
    v = mt_ ? acc_ * ee_ : v;                                                 \
} while (0)

// Rescale v by its wave-max, fold into log-scale S. Every 4 steps.
#define CRF_RENORM do {                                                       \
    float m_ = v;                                                             \
    _Pragma("unroll")                                                         \
    for (int o_ = 32; o_; o_ >>= 1) m_ = fmaxf(m_, __shfl_xor(m_, o_));       \
    float r_ = 1.0f / m_;                                                     \
    v *= r_;                                                                  \
    S += __logf(m_);                                                          \
} while (0)

// Block = 128 threads: wave 0 runs the forward recurrence for batch b,
// wave 1 runs the gold-score gather for batch b (hides under forward's
// 1023-step latency chain and shares L1/L2 with it).
// __launch_bounds__(128, 1): min 1 wave/EU -> full VGPR budget, so Ec[48]
// and the prefetch ring stay in architectural VGPRs (round-1 kernel was
// capped at 60 VGPRs -> per-step spill traffic, 648 cy/step).
__global__ __launch_bounds__(128, 1) void crf_fused(
    const float* __restrict__ emissions, const int* __restrict__ labels,
    const int* __restrict__ mask, const float* __restrict__ trans,
    const float* __restrict__ startt, const float* __restrict__ endt,
    float* __restrict__ gold_out, float* __restrict__ fwd_out)
{
    const int b = blockIdx.x;
    const int tid = threadIdx.x;
    const float* em = emissions + (size_t)b * SEQ * NL;
    const int*   mk = mask + b * SEQ;

    if (tid < 64) {
        // ---------------- wave 0: forward algorithm ----------------
        const int  j   = tid;                  // 0..63, lanes 48..63 idle (v=0)
        const bool act = (j < NL);
        const int  jc  = act ? j : NL - 1;

        // E column j in registers: Ec[i] = exp(T[i][j]); forward uses T[prev][cur].
        float Ec[NL];
        #pragma unroll
        for (int i = 0; i < NL; ++i) {
            float t = trans[i * NL + jc];      // consecutive lanes -> consecutive addrs
            Ec[i] = act ? __expf(t) : 0.0f;
        }

        // init: score0 = start + emit[0]; normalize by wave max.
        float s0 = act ? (startt[jc] + em[jc]) : -3.0e38f;
        float m0 = s0;
        #pragma unroll
        for (int o = 32; o; o >>= 1) m0 = fmaxf(m0, __shfl_xor(m0, o));
        float v = act ? __expf(s0 - m0) : 0.0f;
        float S = m0;

        // 8-deep prefetch ring for emissions + mask (static slot indices only).
        float embuf[8]; int mbuf[8];
        #pragma unroll
        for (int t = 1; t <= 8; ++t) { embuf[t & 7] = em[t * NL + jc]; mbuf[t & 7] = mk[t]; }

        // peeled steps 1..7; renorm before every t with t%4==1 (t>1).
        CRF_STEP(1, 1); CRF_STEP(2, 2); CRF_STEP(3, 3); CRF_STEP(4, 4);
        CRF_RENORM;
        CRF_STEP(5, 5); CRF_STEP(6, 6); CRF_STEP(7, 7);

        // aligned chunks of 8: tb = 8,16,...,1016 covers t = 8..1023.
        for (int tb = 8; tb <= SEQ - 8; tb += 8) {
            CRF_STEP(tb + 0, 0);
            CRF_RENORM;
            CRF_STEP(tb + 1, 1); CRF_STEP(tb + 2, 2); CRF_STEP(tb + 3, 3); CRF_STEP(tb + 4, 4);
            CRF_RENORM;
            CRF_STEP(tb + 5, 5); CRF_STEP(tb + 6, 6); CRF_STEP(tb + 7, 7);
        }

        // fwd = S + log(sum_j v[j] * exp(end[j]))
        float w = act ? v * __expf(endt[jc]) : 0.0f;
        #pragma unroll
        for (int o = 32; o; o >>= 1) w += __shfl_xor(w, o);
        if (j == 0) fwd_out[b] = S + __logf(w);
    } else {
        // ---------------- wave 1: gold score ----------------
        const int l = tid - 64;
        const int* lb = labels + b * SEQ;

        float part = 0.0f; int mcnt = 0;
        for (int t = l; t < SEQ; t += 64) {
            int lt = lb[t];
            int mt = mk[t];
            mcnt += mt;
            if (t == 0) {
                part += startt[lt] + em[lt];
            } else {
                float e  = em[t * NL + lt];
                float tr = trans[lt * NL + lb[t - 1]];   // gold uses T[cur][prev]
                if (mt) part += e + tr;
            }
        }
        #pragma unroll
        for (int o = 32; o; o >>= 1) {
            part += __shfl_xor(part, o);
            mcnt += __shfl_xor(mcnt, o);
        }
        if (l == 0) {
            int len = mcnt - 1;
            gold_out[b] = part + endt[lb[len]];
        }
    }
}

__global__ __launch_bounds__(64) void crf_reduce(
    const float* __restrict__ gold, const float* __restrict__ fwd,
    float* __restrict__ out)
{
    const int l = threadIdx.x;
    float s = 0.0f;
    for (int bIdx = l; bIdx < BATCH; bIdx += 64) s += fwd[bIdx] - gold[bIdx];
    #pragma unroll
    for (int o = 32; o; o >>= 1) s += __shfl_xor(s, o);
    if (l == 0) out[0] = s * (1.0f / (float)BATCH);
}

extern "C" void kernel_launch(void* const* d_in, const int* in_sizes, int n_in,
                              void* d_out, int out_size, void* d_ws, size_t ws_size,
                              hipStream_t stream) {
    const float* emissions = (const float*)d_in[0];
    const int*   labels    = (const int*)d_in[1];
    const int*   mask      = (const int*)d_in[2];
    const float* trans     = (const float*)d_in[3];
    const float* startt    = (const float*)d_in[4];
    const float* endt      = (const float*)d_in[5];
    float*       out       = (float*)d_out;
    float*       wsf       = (float*)d_ws;   // [0..512) gold, [512..1024) fwd

    crf_fused<<<BATCH, 128, 0, stream>>>(emissions, labels, mask, trans, startt, endt,
                                         wsf, wsf + BATCH);
    crf_reduce<<<1, 64, 0, stream>>>(wsf, wsf + BATCH, out);
}